// Round 1
// baseline (669.326 us; speedup 1.0000x reference)
//
#include <hip/hip_runtime.h>
#include <hip/hip_bf16.h>
#include <cstdint>
#include <cstddef>

typedef __bf16 bf16_t;
typedef __bf16 bf16x8 __attribute__((ext_vector_type(8)));
typedef float  f32x4  __attribute__((ext_vector_type(4)));

#define BM 128
#define BN 128
#define BK 32

__device__ __forceinline__ void load16_to_lds(const void* g, void* l) {
  __builtin_amdgcn_global_load_lds(
      (const __attribute__((address_space(1))) void*)g,
      (__attribute__((address_space(3))) void*)l,
      16, 0, 0);
}

// fp32 -> bf16, 8 elements/thread, n multiple of 8
__global__ __launch_bounds__(256) void cvt_f32_to_bf16(const float* __restrict__ in,
                                                       bf16_t* __restrict__ out,
                                                       long n) {
  long i = (long)blockIdx.x * blockDim.x + threadIdx.x;
  long idx = i * 8;
  if (idx >= n) return;
  const float4* p = (const float4*)(in + idx);
  float4 a = p[0], b = p[1];
  bf16x8 o;
  o[0] = (bf16_t)a.x; o[1] = (bf16_t)a.y; o[2] = (bf16_t)a.z; o[3] = (bf16_t)a.w;
  o[4] = (bf16_t)b.x; o[5] = (bf16_t)b.y; o[6] = (bf16_t)b.z; o[7] = (bf16_t)b.w;
  *(bf16x8*)(out + idx) = o;
}

// int32 (values in [-127,127], exact in bf16) -> bf16
__global__ __launch_bounds__(256) void cvt_i32_to_bf16(const int* __restrict__ in,
                                                       bf16_t* __restrict__ out,
                                                       long n) {
  long i = (long)blockIdx.x * blockDim.x + threadIdx.x;
  long idx = i * 8;
  if (idx >= n) return;
  const int4* p = (const int4*)(in + idx);
  int4 a = p[0], b = p[1];
  bf16x8 o;
  o[0] = (bf16_t)(float)a.x; o[1] = (bf16_t)(float)a.y;
  o[2] = (bf16_t)(float)a.z; o[3] = (bf16_t)(float)a.w;
  o[4] = (bf16_t)(float)b.x; o[5] = (bf16_t)(float)b.y;
  o[6] = (bf16_t)(float)b.z; o[7] = (bf16_t)(float)b.w;
  *(bf16x8*)(out + idx) = o;
}

// C[m][n] = sum_k A[m][k] * Bw[n][k];  out = C*scale[n] + bias[n]
// A: [M][K] bf16 row-major, Bw: [N][K] bf16 row-major (B^T-input GEMM).
__global__ __launch_bounds__(256) void gemm_bf16_bt(const bf16_t* __restrict__ A,
                                                    const bf16_t* __restrict__ Bw,
                                                    const float* __restrict__ scale,
                                                    const float* __restrict__ bias,
                                                    float* __restrict__ out,
                                                    int M, int N, int K) {
  // Unpadded row-major tiles: global_load_lds requires lds dst = uniform base + lane*16.
  __shared__ bf16_t As[BM * BK];
  __shared__ bf16_t Bs[BN * BK];

  const int tid  = threadIdx.x;
  const int wave = tid >> 6;
  const int lane = tid & 63;
  const int wm   = wave >> 1;   // wave row in 2x2 wave grid (64 rows each)
  const int wn   = wave & 1;    // wave col
  const int bm   = blockIdx.y;
  const int bn   = blockIdx.x;

  f32x4 acc[4][4] = {};

  // staging: chunk q = tid covers A-tile row q>>2, cols (q&3)*8 .. +8
  const int rowA1 = tid >> 2;
  const int colg  = (tid & 3) * 8;
  const bf16_t* Ag1 = A  + (size_t)(bm * BM + rowA1) * K + colg;
  const bf16_t* Ag2 = Ag1 + (size_t)64 * K;
  const bf16_t* Bg1 = Bw + (size_t)(bn * BN + rowA1) * K + colg;
  const bf16_t* Bg2 = Bg1 + (size_t)64 * K;

  // wave-uniform LDS bases (HW adds lane*16 bytes)
  bf16_t* AsW1 = As + wave * 512;
  bf16_t* AsW2 = As + 2048 + wave * 512;
  bf16_t* BsW1 = Bs + wave * 512;
  bf16_t* BsW2 = Bs + 2048 + wave * 512;

  // MFMA fragment addressing: A[m = lane&15][k = (lane>>4)*8 + j]
  const int fr = lane & 15;
  const int kq = (lane >> 4) * 8;

  for (int k0 = 0; k0 < K; k0 += BK) {
    load16_to_lds(Ag1 + k0, AsW1);
    load16_to_lds(Ag2 + k0, AsW2);
    load16_to_lds(Bg1 + k0, BsW1);
    load16_to_lds(Bg2 + k0, BsW2);
    __syncthreads();   // compiler emits s_waitcnt vmcnt(0) before s_barrier

    bf16x8 af[4], bfr[4];
#pragma unroll
    for (int i = 0; i < 4; ++i) {
      af[i]  = *(const bf16x8*)&As[(wm * 64 + i * 16 + fr) * BK + kq];
      bfr[i] = *(const bf16x8*)&Bs[(wn * 64 + i * 16 + fr) * BK + kq];
    }
#pragma unroll
    for (int m = 0; m < 4; ++m)
#pragma unroll
      for (int n = 0; n < 4; ++n)
        acc[m][n] = __builtin_amdgcn_mfma_f32_16x16x32_bf16(af[m], bfr[n], acc[m][n], 0, 0, 0);

    __syncthreads();   // protect LDS before next iteration's staging
  }

  // Epilogue. C/D layout: col = lane&15, row = (lane>>4)*4 + reg  [m89/m91 verified]
  const int colc = lane & 15;
  const int rq   = (lane >> 4) * 4;
#pragma unroll
  for (int n = 0; n < 4; ++n) {
    const int col = bn * BN + wn * 64 + n * 16 + colc;
    const float sc = scale[col];
    const float bi = bias[col];
#pragma unroll
    for (int m = 0; m < 4; ++m) {
      const int row0 = bm * BM + wm * 64 + m * 16 + rq;
#pragma unroll
      for (int r = 0; r < 4; ++r) {
        out[(size_t)(row0 + r) * N + col] = acc[m][n][r] * sc + bi;
      }
    }
  }
}

extern "C" void kernel_launch(void* const* d_in, const int* in_sizes, int n_in,
                              void* d_out, int out_size, void* d_ws, size_t ws_size,
                              hipStream_t stream) {
  const float* x     = (const float*)d_in[0];
  const int*   w     = (const int*)d_in[1];
  const float* scale = (const float*)d_in[2];
  const float* bias  = (const float*)d_in[3];
  float*       out   = (float*)d_out;

  const int N = in_sizes[3];          // D_OUT = 4096
  const int K = in_sizes[1] / N;      // D_IN  = 4096
  const int M = in_sizes[0] / K;      // B*S   = 8192

  bf16_t* xb = (bf16_t*)d_ws;                 // M*K bf16 = 64 MiB
  bf16_t* wb = xb + (size_t)M * K;            // N*K bf16 = 32 MiB

  const long nx = (long)M * K;
  const long nw = (long)N * K;

  cvt_f32_to_bf16<<<dim3((unsigned)((nx / 8 + 255) / 256)), dim3(256), 0, stream>>>(x, xb, nx);
  cvt_i32_to_bf16<<<dim3((unsigned)((nw / 8 + 255) / 256)), dim3(256), 0, stream>>>(w, wb, nw);

  gemm_bf16_bt<<<dim3(N / BN, M / BM), dim3(256), 0, stream>>>(xb, wb, scale, bias, out, M, N, K);
}

// Round 2
// 467.931 us; speedup vs baseline: 1.4304x; 1.4304x over previous
//
#include <hip/hip_runtime.h>
#include <hip/hip_bf16.h>
#include <cstdint>
#include <cstddef>

typedef int  i32x4 __attribute__((ext_vector_type(4)));

#define BM 128
#define BN 128
#define BK 64   // 64 int8 along K per tile

__device__ __forceinline__ void load16_to_lds(const void* g, void* l) {
  __builtin_amdgcn_global_load_lds(
      (const __attribute__((address_space(1))) void*)g,
      (__attribute__((address_space(3))) void*)l,
      16, 0, 0);
}

// One block (256 thr) per row of x: fused absmax + int8 quantize, row held in regs.
// Writes xq[row][4096] int8 and sx[row] = absmax/127.
__global__ __launch_bounds__(256) void quant_x(const float* __restrict__ x,
                                               char* __restrict__ xq,
                                               float* __restrict__ sx,
                                               int K /*=4096*/) {
  const int row = blockIdx.x;
  const int t   = threadIdx.x;
  const float* xr = x + (size_t)row * K;
  float4 v[4];
  float amax = 0.f;
#pragma unroll
  for (int j = 0; j < 4; ++j) {
    v[j] = ((const float4*)xr)[t + j * 256];
    amax = fmaxf(amax, fmaxf(fmaxf(fabsf(v[j].x), fabsf(v[j].y)),
                             fmaxf(fabsf(v[j].z), fabsf(v[j].w))));
  }
  // wave reduce (64 lanes)
#pragma unroll
  for (int off = 32; off; off >>= 1)
    amax = fmaxf(amax, __shfl_xor(amax, off));
  __shared__ float red[4];
  if ((t & 63) == 0) red[t >> 6] = amax;
  __syncthreads();
  amax = fmaxf(fmaxf(red[0], red[1]), fmaxf(red[2], red[3]));
  amax = fmaxf(amax, 1e-20f);

  const float s = 127.0f / amax;
  int* outw = (int*)(xq + (size_t)row * K);
#pragma unroll
  for (int j = 0; j < 4; ++j) {
    int q0 = __float2int_rn(v[j].x * s);
    int q1 = __float2int_rn(v[j].y * s);
    int q2 = __float2int_rn(v[j].z * s);
    int q3 = __float2int_rn(v[j].w * s);
    int pk = (q0 & 0xff) | ((q1 & 0xff) << 8) | ((q2 & 0xff) << 16) | ((q3 & 0xff) << 24);
    outw[t + j * 256] = pk;
  }
  if (t == 0) sx[row] = amax * (1.0f / 127.0f);
}

// int32 (values in [-127,127]) -> packed int8. One block handles 4096 ints.
__global__ __launch_bounds__(256) void quant_w(const int* __restrict__ w,
                                               char* __restrict__ wq) {
  const size_t base = (size_t)blockIdx.x * 4096;
  const int t = threadIdx.x;
  int* outw = (int*)(wq + base);
#pragma unroll
  for (int j = 0; j < 4; ++j) {
    const int c = t + j * 256;
    int4 a = ((const int4*)(w + base))[c];
    outw[c] = (a.x & 0xff) | ((a.y & 0xff) << 8) | ((a.z & 0xff) << 16) | ((a.w & 0xff) << 24);
  }
}

// C[m][n] = sum_k A[m][k]*Bw[n][k] (int8 x int8 -> int32), then
// out = C * sx[m] * sw[n] + bias[n].   A:[M][K] i8, Bw:[N][K] i8, row-major.
__global__ __launch_bounds__(256) void gemm_i8_bt(const char* __restrict__ A,
                                                  const char* __restrict__ Bw,
                                                  const float* __restrict__ sx,
                                                  const float* __restrict__ sw,
                                                  const float* __restrict__ bias,
                                                  float* __restrict__ out,
                                                  int M, int N, int K) {
  __shared__ char As[BM * BK];   // 8 KiB
  __shared__ char Bs[BN * BK];   // 8 KiB

  const int tid  = threadIdx.x;
  const int wave = tid >> 6;
  const int lane = tid & 63;
  const int wm   = wave >> 1;
  const int wn   = wave & 1;
  const int bm   = blockIdx.y;
  const int bn   = blockIdx.x;

  i32x4 acc[4][4] = {};

  // staging: chunk q covers tile row q>>2, byte cols (q&3)*16..+16; q = tid and tid+256
  const int rowT = tid >> 2;
  const int colg = (tid & 3) * 16;
  const char* Ag1 = A  + (size_t)(bm * BM + rowT) * K + colg;
  const char* Ag2 = Ag1 + (size_t)64 * K;
  const char* Bg1 = Bw + (size_t)(bn * BN + rowT) * K + colg;
  const char* Bg2 = Bg1 + (size_t)64 * K;

  // wave-uniform LDS bases (HW adds lane*16 bytes): chunk q=wave*64+lane -> offset q*16
  char* AsW1 = As + wave * 1024;
  char* AsW2 = As + 4096 + wave * 1024;
  char* BsW1 = Bs + wave * 1024;
  char* BsW2 = Bs + 4096 + wave * 1024;

  // fragment addressing: A[m = lane&15][k = (lane>>4)*16 + j], 16 i8 = 4 VGPRs
  const int fr   = lane & 15;
  const int kq16 = (lane >> 4) * 16;

  for (int k0 = 0; k0 < K; k0 += BK) {
    load16_to_lds(Ag1 + k0, AsW1);
    load16_to_lds(Ag2 + k0, AsW2);
    load16_to_lds(Bg1 + k0, BsW1);
    load16_to_lds(Bg2 + k0, BsW2);
    __syncthreads();

    i32x4 af[4], bf[4];
#pragma unroll
    for (int i = 0; i < 4; ++i) {
      af[i] = *(const i32x4*)&As[(wm * 64 + i * 16 + fr) * BK + kq16];
      bf[i] = *(const i32x4*)&Bs[(wn * 64 + i * 16 + fr) * BK + kq16];
    }
#pragma unroll
    for (int m = 0; m < 4; ++m)
#pragma unroll
      for (int n = 0; n < 4; ++n)
        acc[m][n] = __builtin_amdgcn_mfma_i32_16x16x64_i8(af[m], bf[n], acc[m][n], 0, 0, 0);

    __syncthreads();
  }

  // C/D layout (dtype-independent): col = lane&15, row = (lane>>4)*4 + reg
  const int colc = lane & 15;
  const int rq   = (lane >> 4) * 4;
#pragma unroll
  for (int n = 0; n < 4; ++n) {
    const int col = bn * BN + wn * 64 + n * 16 + colc;
    const float sc = sw[col];
    const float bi = bias[col];
#pragma unroll
    for (int m = 0; m < 4; ++m) {
      const int row0 = bm * BM + wm * 64 + m * 16 + rq;
#pragma unroll
      for (int r = 0; r < 4; ++r) {
        const int row = row0 + r;
        out[(size_t)row * N + col] = (float)acc[m][n][r] * (sx[row] * sc) + bi;
      }
    }
  }
}

extern "C" void kernel_launch(void* const* d_in, const int* in_sizes, int n_in,
                              void* d_out, int out_size, void* d_ws, size_t ws_size,
                              hipStream_t stream) {
  const float* x     = (const float*)d_in[0];
  const int*   w     = (const int*)d_in[1];
  const float* scale = (const float*)d_in[2];
  const float* bias  = (const float*)d_in[3];
  float*       out   = (float*)d_out;

  const int N = in_sizes[3];          // D_OUT = 4096
  const int K = in_sizes[1] / N;      // D_IN  = 4096
  const int M = in_sizes[0] / K;      // B*S   = 8192

  char*  xq = (char*)d_ws;                       // M*K i8  = 32 MiB
  char*  wq = xq + (size_t)M * K;                // N*K i8  = 16 MiB
  float* sx = (float*)(wq + (size_t)N * K);      // M floats

  quant_x<<<dim3(M), dim3(256), 0, stream>>>(x, xq, sx, K);
  quant_w<<<dim3((unsigned)(((size_t)N * K) / 4096)), dim3(256), 0, stream>>>(w, wq);

  gemm_i8_bt<<<dim3(N / BN, M / BM), dim3(256), 0, stream>>>(xq, wq, sx, scale, bias, out, M, N, K);
}

// Round 3
// 450.493 us; speedup vs baseline: 1.4858x; 1.0387x over previous
//
#include <hip/hip_runtime.h>
#include <hip/hip_bf16.h>
#include <cstdint>
#include <cstddef>

typedef int  i32x4 __attribute__((ext_vector_type(4)));

#define BM 128
#define BN 128
#define BK 64   // 64 int8 along K per tile

__device__ __forceinline__ void load16_to_lds(const void* g, void* l) {
  __builtin_amdgcn_global_load_lds(
      (const __attribute__((address_space(1))) void*)g,
      (__attribute__((address_space(3))) void*)l,
      16, 0, 0);
}

// One block (256 thr) per row of x: fused absmax + int8 quantize, row held in regs.
__global__ __launch_bounds__(256) void quant_x(const float* __restrict__ x,
                                               char* __restrict__ xq,
                                               float* __restrict__ sx,
                                               int K /*=4096*/) {
  const int row = blockIdx.x;
  const int t   = threadIdx.x;
  const float* xr = x + (size_t)row * K;
  float4 v[4];
  float amax = 0.f;
#pragma unroll
  for (int j = 0; j < 4; ++j) {
    v[j] = ((const float4*)xr)[t + j * 256];
    amax = fmaxf(amax, fmaxf(fmaxf(fabsf(v[j].x), fabsf(v[j].y)),
                             fmaxf(fabsf(v[j].z), fabsf(v[j].w))));
  }
#pragma unroll
  for (int off = 32; off; off >>= 1)
    amax = fmaxf(amax, __shfl_xor(amax, off));
  __shared__ float red[4];
  if ((t & 63) == 0) red[t >> 6] = amax;
  __syncthreads();
  amax = fmaxf(fmaxf(red[0], red[1]), fmaxf(red[2], red[3]));
  amax = fmaxf(amax, 1e-20f);

  const float s = 127.0f / amax;
  int* outw = (int*)(xq + (size_t)row * K);
#pragma unroll
  for (int j = 0; j < 4; ++j) {
    int q0 = __float2int_rn(v[j].x * s);
    int q1 = __float2int_rn(v[j].y * s);
    int q2 = __float2int_rn(v[j].z * s);
    int q3 = __float2int_rn(v[j].w * s);
    int pk = (q0 & 0xff) | ((q1 & 0xff) << 8) | ((q2 & 0xff) << 16) | ((q3 & 0xff) << 24);
    outw[t + j * 256] = pk;
  }
  if (t == 0) sx[row] = amax * (1.0f / 127.0f);
}

// int32 (values in [-127,127]) -> packed int8. One block handles 4096 ints.
__global__ __launch_bounds__(256) void quant_w(const int* __restrict__ w,
                                               char* __restrict__ wq) {
  const size_t base = (size_t)blockIdx.x * 4096;
  const int t = threadIdx.x;
  int* outw = (int*)(wq + base);
#pragma unroll
  for (int j = 0; j < 4; ++j) {
    const int c = t + j * 256;
    int4 a = ((const int4*)(w + base))[c];
    outw[c] = (a.x & 0xff) | ((a.y & 0xff) << 8) | ((a.z & 0xff) << 16) | ((a.w & 0xff) << 24);
  }
}

// C[m][n] = sum_k A[m][k]*Bw[n][k] (int8 -> int32); out = C*sx[m]*sw[n] + bias[n].
// XOR-swizzled LDS (kills 64B-row-stride bank conflicts) + 2-buffer pipelined staging
// (one barrier/iter; global_load_lds for k+1 issued before computing k).
__global__ __launch_bounds__(256) void gemm_i8_bt(const char* __restrict__ A,
                                                  const char* __restrict__ Bw,
                                                  const float* __restrict__ sx,
                                                  const float* __restrict__ sw,
                                                  const float* __restrict__ bias,
                                                  float* __restrict__ out,
                                                  int M, int N, int K) {
  // Swizzle map: LDS 16B-chunk q (0..511 per tile) holds global k-chunk
  // jg = (q&3) ^ ((q>>3)&3) of row r = q>>2. Chunk q sits at byte q*16
  // (global_load_lds: dst = wave-uniform base + lane*16).
  __shared__ char As[2][BM * BK];   // 2 x 8 KiB
  __shared__ char Bs[2][BN * BK];   // 2 x 8 KiB

  const int tid  = threadIdx.x;
  const int wave = tid >> 6;
  const int lane = tid & 63;
  const int wm   = wave >> 1;
  const int wn   = wave & 1;
  const int bm   = blockIdx.y;
  const int bn   = blockIdx.x;

  i32x4 acc[4][4] = {};

  // Staging: thread stages chunks q=tid and q=tid+256 of each tile.
  const int rowT = tid >> 2;
  const int jg   = ((tid & 3) ^ ((tid >> 3) & 3)) * 16;   // swizzled global k-chunk byte col
  const char* Ag1 = A  + (size_t)(bm * BM + rowT) * K + jg;
  const char* Ag2 = Ag1 + (size_t)64 * K;
  const char* Bg1 = Bw + (size_t)(bn * BN + rowT) * K + jg;
  const char* Bg2 = Bg1 + (size_t)64 * K;

  const int ldsOff1 = wave * 1024;          // chunk q=tid       -> byte tid*16
  const int ldsOff2 = 4096 + wave * 1024;   // chunk q=tid+256

  // Fragment read offsets (constant across K): row R, k-chunk j=lane>>4 lives at
  // byte R*64 + (j ^ ((R>>1)&3))*16; (R>>1)&3 == (fr>>1)&3 since wave/i offsets are %16==0.
  const int fr  = lane & 15;
  const int swz = ((lane >> 4) ^ ((fr >> 1) & 3)) * 16;
  int offA[4], offB[4];
#pragma unroll
  for (int i = 0; i < 4; ++i) {
    offA[i] = (wm * 64 + i * 16 + fr) * 64 + swz;
    offB[i] = (wn * 64 + i * 16 + fr) * 64 + swz;
  }

  // Prologue: stage tile 0 into buffer 0.
  load16_to_lds(Ag1, &As[0][ldsOff1]);
  load16_to_lds(Ag2, &As[0][ldsOff2]);
  load16_to_lds(Bg1, &Bs[0][ldsOff1]);
  load16_to_lds(Bg2, &Bs[0][ldsOff2]);

  int kb = 0;
  for (int k0 = 0; k0 < K; k0 += BK) {
    __syncthreads();   // drains vmcnt: buf[kb] ready; prev iter's frag reads done -> buf[kb^1] free

    if (k0 + BK < K) {  // stage next tile while computing this one
      load16_to_lds(Ag1 + k0 + BK, &As[kb ^ 1][ldsOff1]);
      load16_to_lds(Ag2 + k0 + BK, &As[kb ^ 1][ldsOff2]);
      load16_to_lds(Bg1 + k0 + BK, &Bs[kb ^ 1][ldsOff1]);
      load16_to_lds(Bg2 + k0 + BK, &Bs[kb ^ 1][ldsOff2]);
    }

    i32x4 af[4], bf[4];
#pragma unroll
    for (int i = 0; i < 4; ++i) {
      af[i] = *(const i32x4*)&As[kb][offA[i]];
      bf[i] = *(const i32x4*)&Bs[kb][offB[i]];
    }
#pragma unroll
    for (int m = 0; m < 4; ++m)
#pragma unroll
      for (int n = 0; n < 4; ++n)
        acc[m][n] = __builtin_amdgcn_mfma_i32_16x16x64_i8(af[m], bf[n], acc[m][n], 0, 0, 0);

    kb ^= 1;
  }

  // C/D layout (dtype-independent): col = lane&15, row = (lane>>4)*4 + reg
  const int colc = lane & 15;
  const int rq   = (lane >> 4) * 4;
#pragma unroll
  for (int n = 0; n < 4; ++n) {
    const int col = bn * BN + wn * 64 + n * 16 + colc;
    const float sc = sw[col];
    const float bi = bias[col];
#pragma unroll
    for (int m = 0; m < 4; ++m) {
      const int row0 = bm * BM + wm * 64 + m * 16 + rq;
#pragma unroll
      for (int r = 0; r < 4; ++r) {
        const int row = row0 + r;
        out[(size_t)row * N + col] = (float)acc[m][n][r] * (sx[row] * sc) + bi;
      }
    }
  }
}

extern "C" void kernel_launch(void* const* d_in, const int* in_sizes, int n_in,
                              void* d_out, int out_size, void* d_ws, size_t ws_size,
                              hipStream_t stream) {
  const float* x     = (const float*)d_in[0];
  const int*   w     = (const int*)d_in[1];
  const float* scale = (const float*)d_in[2];
  const float* bias  = (const float*)d_in[3];
  float*       out   = (float*)d_out;

  const int N = in_sizes[3];          // D_OUT = 4096
  const int K = in_sizes[1] / N;      // D_IN  = 4096
  const int M = in_sizes[0] / K;      // B*S   = 8192

  char*  xq = (char*)d_ws;                       // M*K i8  = 32 MiB
  char*  wq = xq + (size_t)M * K;                // N*K i8  = 16 MiB
  float* sx = (float*)(wq + (size_t)N * K);      // M floats

  quant_x<<<dim3(M), dim3(256), 0, stream>>>(x, xq, sx, K);
  quant_w<<<dim3((unsigned)(((size_t)N * K) / 4096)), dim3(256), 0, stream>>>(w, wq);

  gemm_i8_bt<<<dim3(N / BN, M / BM), dim3(256), 0, stream>>>(xq, wq, sx, scale, bias, out, M, N, K);
}